// Round 4
// baseline (141.771 us; speedup 1.0000x reference)
//
#include <hip/hip_runtime.h>
#include <math.h>

#define BLOCK 256
#define NN 100
#define GB 10           // boxes per pass-B block (one sorted group)
#define NGRP (NN / GB)  // 10 box-groups per image
#define SPLIT 16        // anchor-dimension splits for pass B
#define NBINS 4096      // 64 x-cells * 64 y-cells (16px each) for anchors
#define BMAX 8
#define HS_THREADS 1024

__device__ __forceinline__ float fast_rcp(float x) { return __builtin_amdgcn_rcpf(x); }

__device__ __forceinline__ int cell_key(float cx, float cy) {
    int kx = (int)(cx * (64.0f / 1024.0f));
    int ky = (int)(cy * (64.0f / 1024.0f));
    kx = kx < 0 ? 0 : (kx > 63 ? 63 : kx);
    ky = ky < 0 ? 0 : (ky > 63 ? 63 : ky);
    return (kx << 6) | ky;
}

// 8x8 Morton key for boxes (128px cells) -> sorted groups are spatially tight
__device__ __forceinline__ int box_key(float cx, float cy) {
    int kx = (int)(cx * (8.0f / 1024.0f));
    int ky = (int)(cy * (8.0f / 1024.0f));
    kx = kx < 0 ? 0 : (kx > 7 ? 7 : kx);
    ky = ky < 0 ? 0 : (ky > 7 ? 7 : ky);
    return (kx & 1) | ((ky & 1) << 1) | ((kx & 2) << 1) | ((ky & 2) << 2)
         | ((kx & 4) << 2) | ((ky & 4) << 3);
}

// ---------------------------------------------------------------------------
// ONE single-block kernel replacing memset+hist+scan (3 dispatches in R3):
//  - anchor cell histogram in LDS (16 KB), block-scan, write offsets
//  - per-image Morton rank-sort of the 100 boxes + per-group-of-10 bboxes
// 1024 threads; ~1 MB anchor read through one CU ~7 us, everything else tiny.
// ---------------------------------------------------------------------------
__global__ void __launch_bounds__(HS_THREADS) bbp_histscan(
    const float* __restrict__ anchors, const float* __restrict__ bboxes,
    int* __restrict__ hist, int* __restrict__ sorted_box_id,
    float* __restrict__ gbox, int A, int B) {
    __shared__ int h[NBINS];
    __shared__ float4 sbx[BMAX * NN];
    __shared__ int bkey[BMAX * NN];
    __shared__ int sid[BMAX * NN];
    __shared__ int wsum[HS_THREADS / 64];
    const int tid = threadIdx.x;
    const int lane = tid & 63, wid = tid >> 6;

    for (int i = tid; i < NBINS; i += HS_THREADS) h[i] = 0;
    __syncthreads();
    for (int i = tid; i < A; i += HS_THREADS) {
        float2 p = *(const float2*)(anchors + (size_t)i * 4);
        atomicAdd(&h[cell_key(p.x, p.y)], 1);
    }
    __syncthreads();

    // block exclusive scan: thread owns bins [4t, 4t+4)
    int b0 = h[4 * tid], b1 = h[4 * tid + 1], b2 = h[4 * tid + 2], b3 = h[4 * tid + 3];
    int s = b0 + b1 + b2 + b3;
    int incl = s;
    #pragma unroll
    for (int off = 1; off < 64; off <<= 1) {
        int o = __shfl_up(incl, off, 64);
        if (lane >= off) incl += o;
    }
    if (lane == 63) wsum[wid] = incl;
    __syncthreads();
    if (wid == 0 && lane < HS_THREADS / 64) {
        int v = wsum[lane], iv = v;
        #pragma unroll
        for (int off = 1; off < HS_THREADS / 64; off <<= 1) {
            int o = __shfl_up(iv, off, 64);
            if (lane >= off) iv += o;
        }
        wsum[lane] = iv - v;   // exclusive
    }
    __syncthreads();
    int ex = wsum[wid] + (incl - s);
    h[4 * tid] = ex;
    h[4 * tid + 1] = ex + b0;
    h[4 * tid + 2] = ex + b0 + b1;
    h[4 * tid + 3] = ex + b0 + b1 + b2;
    __syncthreads();
    for (int i = tid; i < NBINS; i += HS_THREADS) hist[i] = h[i];

    // ---- box sort (orig indices preserved; pass B is order-independent) ----
    const int BN = B * NN;
    if (tid < BN) {
        float4 v = *(const float4*)(bboxes + (size_t)tid * 4);
        sbx[tid] = v;
        bkey[tid] = box_key((v.x + v.z) * 0.5f, (v.y + v.w) * 0.5f);
    }
    __syncthreads();
    if (tid < BN) {
        int b = tid / NN, n = tid - b * NN, k = bkey[tid];
        const int base = b * NN;
        int r = 0;
        for (int m = 0; m < NN; ++m) {
            int km = bkey[base + m];
            r += (km < k) || (km == k && m < n);
        }
        sid[base + r] = n;
    }
    __syncthreads();
    if (tid < BN) sorted_box_id[tid] = sid[tid];
    if (tid < B * NGRP) {
        int b = tid / NGRP, ng = tid - b * NGRP;
        float x1 = 3e38f, y1 = 3e38f, x2 = -3e38f, y2 = -3e38f;
        #pragma unroll
        for (int g = 0; g < GB; ++g) {
            int n = sid[b * NN + ng * GB + g];
            float4 v = sbx[b * NN + n];
            x1 = fminf(x1, v.x); y1 = fminf(y1, v.y);
            x2 = fmaxf(x2, v.z); y2 = fmaxf(y2, v.w);
        }
        *(float4*)(gbox + (size_t)tid * 4) = make_float4(x1, y1, x2, y2);
    }
}

__global__ void __launch_bounds__(BLOCK) bbp_scatter(
    const float* __restrict__ anchors, int* __restrict__ off,
    float4* __restrict__ scor, float2* __restrict__ smeta, int A) {
    int i = blockIdx.x * BLOCK + threadIdx.x;
    if (i >= A) return;
    float4 ac = *(const float4*)(anchors + (size_t)i * 4);
    int pos = atomicAdd(&off[cell_key(ac.x, ac.y)], 1);
    float4 c;
    c.x = fmaf(ac.z, -0.5f, ac.x);
    c.y = fmaf(ac.w, -0.5f, ac.y);
    c.z = fmaf(ac.z, 0.5f, ac.x);
    c.w = fmaf(ac.w, 0.5f, ac.y);
    scor[pos] = c;                             // pre-decoded corners
    smeta[pos] = make_float2(ac.z * ac.w, __int_as_float(i));  // area, orig idx
}

// ---------------------------------------------------------------------------
// Fused match on SORTED anchors with nested ballot skip.
// CORRECTNESS KEY: init (inter=0, s=1, idx=0) -> update test degenerates to
// inter > 0; skipped (zero-IoU) pairs can never win; all-skip rows/cols keep
// idx=0 = reference argmax-of-zeros.
// Pass B additionally uses SORTED BOX GROUPS: one ballot vs the group bbox
// per 64-anchor iter skips all GB inner ballots (group bbox contains each
// member box, so skipped pairs are provably inter==0). Winner selection is
// order-independent (packed (iou, ~orig_anchor) max, slot = orig box id).
// Pass A keeps ORIGINAL box order (tie semantics identical to reference).
// ---------------------------------------------------------------------------
__global__ void __launch_bounds__(BLOCK, 4) bbp_fused(
    const float4* __restrict__ scor, const float2* __restrict__ smeta,
    const float* __restrict__ bboxes,
    const int* __restrict__ sorted_box_id, const float* __restrict__ gbox,
    float2* __restrict__ pa,                      // [B*A] (row max iou, idx)
    unsigned long long* __restrict__ packed_part, // [B,N,SPLIT]
    int A, int NA, int NBB) {
    const int bid = blockIdx.x;
    const int tid = threadIdx.x;

    if (bid < NBB) {
        // ========== pass B: per-box partial max over one sorted slab ========
        const int b   = bid / (NGRP * SPLIT);
        const int rem = bid - b * (NGRP * SPLIT);
        const int ng  = rem / SPLIT;
        const int sp  = rem - ng * SPLIT;
        const int n0  = ng * GB;
        const int SA  = A / SPLIT;                // 4096 anchors per slab
        const int abase = sp * SA;
        const int* sbid = sorted_box_id + b * NN + n0;

        float bx1[GB], by1[GB], bx2[GB], by2[GB], sa[GB];
        #pragma unroll
        for (int g = 0; g < GB; ++g) {
            int n = sbid[g];                             // uniform -> s_load
            float4 v = *(const float4*)(bboxes + ((size_t)b * NN + n) * 4);
            bx1[g] = v.x; by1[g] = v.y; bx2[g] = v.z; by2[g] = v.w;
            sa[g] = (v.z - v.x) * (v.w - v.y);
        }
        const float4 gb4 = *(const float4*)(gbox + ((size_t)b * NGRP + ng) * 4);

        float cin[GB], cs[GB];
        int cai[GB];
        #pragma unroll
        for (int g = 0; g < GB; ++g) { cin[g] = 0.0f; cs[g] = 1.0f; cai[g] = 0; }

        const int iters = SA >> 8;                       // 16
        #pragma unroll 2
        for (int j = 0; j < iters; ++j) {
            const int t = abase + j * BLOCK + tid;
            const float4 c = scor[t];                    // coalesced
            // group-level wave skip (covers all GB boxes)
            float gw = fminf(c.z, gb4.z) - fmaxf(c.x, gb4.x);
            if (!__any(gw > 0.0f)) continue;
            float gh = fminf(c.w, gb4.w) - fmaxf(c.y, gb4.y);
            if (!__any(gh > 0.0f)) continue;
            const float2 m = smeta[t];
            const float area_a = m.x;
            const int orig = __float_as_int(m.y);
            #pragma unroll
            for (int g = 0; g < GB; ++g) {
                float w0 = fminf(c.z, bx2[g]) - fmaxf(c.x, bx1[g]);
                if (__any(w0 > 0.0f)) {                  // per-box x skip
                    float h0 = fminf(c.w, by2[g]) - fmaxf(c.y, by1[g]);
                    if (__any(h0 > 0.0f)) {              // per-box y skip
                        float inter = fmaxf(w0, 0.0f) * fmaxf(h0, 0.0f);
                        float s = area_a + sa[g];
                        if (fmaf(inter, cs[g], -(cin[g] * s)) > 0.0f) {
                            cin[g] = inter; cs[g] = s; cai[g] = orig;
                        }
                    }
                }
            }
        }

        // once-per-block combine: shfl-u64 wave reduce -> LDS -> plain store
        __shared__ unsigned long long sred[GB][BLOCK / 64];
        #pragma unroll
        for (int g = 0; g < GB; ++g) {
            float iou = fmaxf(cin[g] * fast_rcp(cs[g] - cin[g]), 0.0f);
            unsigned long long pk =
                ((unsigned long long)__float_as_uint(iou) << 32)
                | (unsigned long long)(0xFFFFFFFFu - (unsigned)cai[g]);
            #pragma unroll
            for (int off = 32; off > 0; off >>= 1) {
                unsigned long long o = __shfl_down(pk, off, 64);
                if (o > pk) pk = o;
            }
            if ((tid & 63) == 0) sred[g][tid >> 6] = pk;
        }
        __syncthreads();
        if (tid < GB) {
            unsigned long long mx = sred[tid][0];
            #pragma unroll
            for (int j = 1; j < BLOCK / 64; ++j) {
                unsigned long long o = sred[tid][j];
                if (o > mx) mx = o;
            }
            // slot indexed by ORIGINAL box id
            packed_part[((size_t)b * NN + sbid[tid]) * SPLIT + sp] = mx;
        }
    } else {
        // ========== pass A: per-anchor row max over boxes (ORIG order) ======
        const int abid = bid - NBB;
        const int b = abid / NA;
        const int t = (abid - b * NA) * BLOCK + tid;     // sorted position

        __shared__ float sbarea[NN];
        if (tid < NN) {
            float4 v = *(const float4*)(bboxes + ((size_t)b * NN + tid) * 4);
            sbarea[tid] = (v.z - v.x) * (v.w - v.y);
        }
        __syncthreads();

        const float4 c = scor[t];
        const float2 mt = smeta[t];
        const float area_a = mt.x;
        const int orig = __float_as_int(mt.y);
        const float* bbase = bboxes + (size_t)b * NN * 4;   // wave-uniform

        float in0 = 0.0f, s0 = 1.0f;
        int i0 = 0;
        #pragma unroll 4
        for (int n = 0; n < NN; ++n) {
            const float4 v = *(const float4*)(bbase + 4 * n);  // s_load
            float w0 = fminf(c.z, v.z) - fmaxf(c.x, v.x);
            if (__any(w0 > 0.0f)) {
                float h0 = fminf(c.w, v.w) - fmaxf(c.y, v.y);
                if (__any(h0 > 0.0f)) {
                    float inter = fmaxf(w0, 0.0f) * fmaxf(h0, 0.0f);
                    float s = area_a + sbarea[n];
                    if (fmaf(inter, s0, -(in0 * s)) > 0.0f) {
                        in0 = inter; s0 = s; i0 = n;
                    }
                }
            }
        }
        const size_t idx = (size_t)b * A + orig;
        float2 r;
        r.x = in0 * fast_rcp(s0 - in0);   // zero row -> 0
        r.y = __int_as_float(i0);
        pa[idx] = r;                                     // scattered 8B, L2
    }
}

// ---------------------------------------------------------------------------
// Finalize: reduce SPLIT partials per box in LDS, override scatter via LDS
// atomicMax, score + one-hot conf + delta encoding. (Unchanged from R3.)
// ---------------------------------------------------------------------------
__global__ void __launch_bounds__(BLOCK) bbp_finalize(
    const float* __restrict__ anchors, const float* __restrict__ bboxes,
    const int* __restrict__ labels, const float* __restrict__ mean4,
    const float* __restrict__ std4, const float* __restrict__ thr_p,
    const float2* __restrict__ pa,
    const unsigned long long* __restrict__ packed_part,
    float* __restrict__ out_conf, float* __restrict__ out_deltas,
    int A, int C) {
    const int b = blockIdx.y;
    const int tid = threadIdx.x;

    __shared__ float smax[NN];    // max_iou_of_bbox
    __shared__ float4 sbox[NN];   // gt boxes
    __shared__ int slab[NN];      // labels
    __shared__ int sovr[BLOCK];   // override winner per local anchor (-1 none)
    sovr[tid] = -1;
    __syncthreads();
    if (tid < NN) {
        const ulonglong2* pp =
            (const ulonglong2*)(packed_part + ((size_t)b * NN + tid) * SPLIT);
        unsigned long long m = 0;
        #pragma unroll
        for (int j = 0; j < SPLIT / 2; ++j) {
            ulonglong2 v = pp[j];
            if (v.x > m) m = v.x;
            if (v.y > m) m = v.y;
        }
        smax[tid] = __uint_as_float((unsigned)(m >> 32));
        unsigned an = 0xFFFFFFFFu - (unsigned)(m & 0xFFFFFFFFull);
        // segment_max over target ids: larger n wins -> atomicMax
        if ((an >> 8) == (unsigned)blockIdx.x)
            atomicMax(&sovr[an & (BLOCK - 1)], tid);
        slab[tid] = labels[(size_t)b * NN + tid];
        sbox[tid] = *(const float4*)(bboxes + ((size_t)b * NN + tid) * 4);
    }
    __syncthreads();

    const int a = blockIdx.x * BLOCK + tid;
    const size_t idx = (size_t)b * A + a;
    const float thr = thr_p[0];

    float2 pav = pa[idx];
    int ov = sovr[tid];
    bool valid = ov >= 0;
    int bi = valid ? ov : __float_as_int(pav.y);
    float mb = smax[bi];                      // max_iou_of_bbox[bi]
    float miou = valid ? mb : pav.x;
    float denom = fmaxf(mb, thr);
    if (miou < 0.5f * thr) miou = 0.0f;
    float score = miou * fast_rcp(denom);
    int lab = slab[bi];
    if (lab <= 0) { score = 0.0f; lab = 0; }

    for (int c = 0; c < C; ++c)
        out_conf[idx * (size_t)C + c] = (lab == c + 1) ? score : 0.0f;

    float4 bv = sbox[bi];
    float4 av = *(const float4*)(anchors + (size_t)a * 4);
    float cx = (bv.x + bv.z) * 0.5f;
    float cy = (bv.y + bv.w) * 0.5f;
    float bw = bv.z - bv.x;
    float bh = bv.w - bv.y;
    const float rz = fast_rcp(av.z), rw = fast_rcp(av.w);
    float4 d;
    d.x = ((cx - av.x) * rz - mean4[0]) * fast_rcp(std4[0]);
    d.y = ((cy - av.y) * rw - mean4[1]) * fast_rcp(std4[1]);
    d.z = (__logf(bw * rz) - mean4[2]) * fast_rcp(std4[2]);
    d.w = (__logf(bh * rw) - mean4[3]) * fast_rcp(std4[3]);
    *(float4*)(out_deltas + idx * 4) = d;
}

// ---------------------------------------------------------------------------
extern "C" void kernel_launch(void* const* d_in, const int* in_sizes, int n_in,
                              void* d_out, int out_size, void* d_ws, size_t ws_size,
                              hipStream_t stream) {
    const float* anchors = (const float*)d_in[0];
    const int* labels = (const int*)d_in[1];
    const float* bboxes = (const float*)d_in[2];
    const float* mean4 = (const float*)d_in[3];
    const float* std4 = (const float*)d_in[4];
    const float* thr_p = (const float*)d_in[5];

    const int A = in_sizes[0] / 4;        // 65536
    const int BN = in_sizes[1];           // 800
    const int B = BN / NN;                // 8
    const int C = out_size / (B * A) - 4; // 1
    const int NA = A / BLOCK;             // 256 pass-A block-groups per image
    const int NAB = B * NA;               // 2048 pass-A blocks
    const int NBB = B * NGRP * SPLIT;     // 1280 pass-B blocks

    char* ws = (char*)d_ws;
    size_t off = 0;
    int* hist = (int*)ws;                                         // [4096]
    off += ((size_t)NBINS * sizeof(int) + 255) & ~(size_t)255;
    float4* scor = (float4*)(ws + off);                           // [A]
    off += ((size_t)A * sizeof(float4) + 255) & ~(size_t)255;
    float2* smeta = (float2*)(ws + off);                          // [A]
    off += ((size_t)A * sizeof(float2) + 255) & ~(size_t)255;
    unsigned long long* packed_part = (unsigned long long*)(ws + off); // [B*N*SPLIT]
    off += ((size_t)B * NN * SPLIT * sizeof(unsigned long long) + 255) & ~(size_t)255;
    float2* pa = (float2*)(ws + off);                             // [B*A]
    off += ((size_t)B * A * sizeof(float2) + 255) & ~(size_t)255;
    int* sorted_box_id = (int*)(ws + off);                        // [B*N]
    off += ((size_t)B * NN * sizeof(int) + 255) & ~(size_t)255;
    float* gbox = (float*)(ws + off);                             // [B*NGRP*4]

    float* out_conf = (float*)d_out;
    float* out_deltas = out_conf + (size_t)B * A * C;

    bbp_histscan<<<dim3(1), dim3(HS_THREADS), 0, stream>>>(
        anchors, bboxes, hist, sorted_box_id, gbox, A, B);

    bbp_scatter<<<dim3(A / BLOCK), dim3(BLOCK), 0, stream>>>(anchors, hist, scor, smeta, A);

    bbp_fused<<<dim3(NBB + NAB), dim3(BLOCK), 0, stream>>>(
        scor, smeta, bboxes, sorted_box_id, gbox, pa, packed_part, A, NA, NBB);

    bbp_finalize<<<dim3(A / BLOCK, B), dim3(BLOCK), 0, stream>>>(
        anchors, bboxes, labels, mean4, std4, thr_p, pa, packed_part,
        out_conf, out_deltas, A, C);
}